// Round 3
// baseline (572.790 us; speedup 1.0000x reference)
//
#include <hip/hip_runtime.h>
#include <hip/hip_bf16.h>

// Problem constants (RecurrentGemma RG-LRU): B=4, S=2048, D=2560, H=10, bw=256
#define B_  4
#define S_  2048
#define D_  2560
#define H_  10
#define BW_ 256
#define NC_ 32           // chunks per sequence
#define L_  64           // steps per chunk
#define NCHAIN (B_ * H_) // 40 carry chains (b, h); each chain has NC_ links
#define NBLK (NCHAIN * NC_)  // 1280 blocks

typedef _Float16 f16;
typedef _Float16 f16x4 __attribute__((ext_vector_type(4)));
typedef _Float16 f16x8 __attribute__((ext_vector_type(8)));
typedef float    f32x4 __attribute__((ext_vector_type(4)));
typedef unsigned int uint32;

// ---------------------------------------------------------------------------
// Prep: transpose+convert weights to fp16 [H][N][K] via LDS 64x64 tiles
// (coalesced reads AND writes), plus softplus(recurrent_param).
// ---------------------------------------------------------------------------
__global__ __launch_bounds__(256) void prep_kernel(
    const float* __restrict__ wig, const float* __restrict__ wrg,
    const float* __restrict__ rp,
    f16* __restrict__ wt_ig, f16* __restrict__ wt_rg, float* __restrict__ sp)
{
    __shared__ f16 tl[64 * 68];   // +4 pad breaks bank alignment
    const int it = blockIdx.x, jt = blockIdx.y, h = blockIdx.z;
    const int tid = threadIdx.x;

    int flat = ((blockIdx.z * 4 + blockIdx.y) * 4 + blockIdx.x) * 256 + tid;
    if (flat < D_) {
        float x = rp[flat];
        sp[flat] = (x > 20.f) ? x : log1pf(__expf(x));
    }

    for (int m = 0; m < 2; m++) {
        const float* W = m ? wrg : wig;
        f16* WT = m ? wt_rg : wt_ig;
        if (m) __syncthreads();   // m=0 LDS reads done before overwrite
        #pragma unroll
        for (int p = 0; p < 4; p++) {
            int idx = p * 256 + tid;
            int il = idx >> 4, j4 = (idx & 15) << 2;
            float4 v = *(const float4*)&W[(h << 16) + ((it * 64 + il) << 8)
                                          + jt * 64 + j4];
            f16x4 hv;
            hv[0] = (f16)v.x; hv[1] = (f16)v.y; hv[2] = (f16)v.z; hv[3] = (f16)v.w;
            *(f16x4*)&tl[il * 68 + j4] = hv;
        }
        __syncthreads();
        #pragma unroll
        for (int p = 0; p < 4; p++) {
            int idx = p * 256 + tid;
            int jl = idx >> 4, i4 = (idx & 15) << 2;
            f16x4 hv;
            hv[0] = tl[(i4 + 0) * 68 + jl];
            hv[1] = tl[(i4 + 1) * 68 + jl];
            hv[2] = tl[(i4 + 2) * 68 + jl];
            hv[3] = tl[(i4 + 3) * 68 + jl];
            *(f16x4*)&WT[(h << 16) + ((jt * 64 + jl) << 8) + it * 64 + i4] = hv;
        }
    }
}

// ---------------------------------------------------------------------------
// Fully fused: gate-GEMM + chunk scan + decoupled-lookback carry + apply.
// Block (via ticket): chain = (h, b), link c. 512 threads = 8 waves:
//   w>>1 = col quadrant (64 of 256 head cols), w&1 = gate (0=in, 1=rec).
// LDS: lds1 = A-tile f16[64][256] (swz), reused as igate then ys.
//      lds2 = log_a f16[64][256] (swz), reused as Acum.
// Carry protocol: publish per-column (Hend,Pprod) f32 -> release flag;
// wait on flags of all j<c (ticket order makes this deadlock-free), fold.
// ---------------------------------------------------------------------------
__global__ __launch_bounds__(512, 4) void fused_kernel(
    const float* __restrict__ act,
    const f16* __restrict__ wt_ig, const f16* __restrict__ wt_rg,
    const float* __restrict__ big, const float* __restrict__ brg,
    const float* __restrict__ sp,
    float* __restrict__ He, float* __restrict__ Pp,
    int* __restrict__ flags, int* __restrict__ counter,
    float* __restrict__ out)
{
    __shared__ f16 lds1[64 * 256];
    __shared__ f16 lds2[64 * 256];
    __shared__ float carry_lds[256];
    __shared__ int ticket_s;

    const int tid = threadIdx.x;
    if (tid == 0) ticket_s = atomicAdd(counter, 1);
    __syncthreads();
    const int t = ticket_s;
    const int c = t & 31;            // chunk within chain
    const int chain = t >> 5;        // 0..39
    const int b = chain & 3, h = chain >> 2;
    const int r0 = (b << 11) + (c << 6);   // global row of chunk start

    const int lane = tid & 63, w = tid >> 6;
    const int gate = w & 1;
    const int n0 = (w >> 1) * 64;          // head-col base of this wave
    const int l16 = lane & 15, lhi = lane >> 4;

    // ---- Phase 1: stage A tile (64 rows x 256 k) fp32 -> fp16, swizzled
    {
        const float* abase = act + (size_t)r0 * D_ + (h << 8);
        #pragma unroll
        for (int i = 0; i < 8; i++) {
            int f = i * 512 + tid;            // float4 index, 4096 total
            int row = f >> 6;
            int k4 = (f & 63) << 2;
            float4 v = *(const float4*)(abase + (size_t)row * D_ + k4);
            f16x4 hv;
            hv[0] = (f16)v.x; hv[1] = (f16)v.y; hv[2] = (f16)v.z; hv[3] = (f16)v.w;
            *(f16x4*)&lds1[row * 256 + (k4 ^ ((row & 7) << 3))] = hv;
        }
    }
    __syncthreads();

    // ---- Phase 2: GEMM. Each wave: 64 rows x 64 cols x one gate, K=256
    const f16* wbase = (gate ? wt_rg : wt_ig) + (h << 16);
    f32x4 acc[4][4] = {};
    f16x8 ar[2][4], br[2][4];

    auto LDA = [&](int ks, f16x8* dst) {
        #pragma unroll
        for (int fm = 0; fm < 4; fm++) {
            int row = fm * 16 + l16;
            int k = ks * 32 + lhi * 8;
            dst[fm] = *(const f16x8*)&lds1[row * 256 + (k ^ ((row & 7) << 3))];
        }
    };
    auto LDB = [&](int ks, f16x8* dst) {
        int ka = ks * 32 + lhi * 8;
        #pragma unroll
        for (int fn = 0; fn < 4; fn++) {
            int j = n0 + fn * 16 + l16;
            dst[fn] = *(const f16x8*)(wbase + (j << 8) + ka);
        }
    };

    LDA(0, ar[0]); LDB(0, br[0]);
    #pragma unroll
    for (int ks = 0; ks < 8; ks++) {
        const int cur = ks & 1;
        if (ks < 7) { LDA(ks + 1, ar[cur ^ 1]); LDB(ks + 1, br[cur ^ 1]); }
        #pragma unroll
        for (int fm = 0; fm < 4; fm++)
        #pragma unroll
        for (int fn = 0; fn < 4; fn++)
            acc[fm][fn] = __builtin_amdgcn_mfma_f32_16x16x32_f16(
                ar[cur][fm], br[cur][fn], acc[fm][fn], 0, 0, 0);
    }
    __syncthreads();   // all lds1 (A-tile) reads complete before overwrite

    // ---- Phase 3: epilogue -> igate (lds1) / log_a (lds2), f16 swizzled
    {
        const float* biasp = gate ? brg : big;
        f16* ldst = gate ? lds2 : lds1;
        #pragma unroll
        for (int fn = 0; fn < 4; fn++) {
            int coll = n0 + fn * 16 + l16;         // block-local col 0..255
            int dcol = (h << 8) + coll;
            float bias = biasp[dcol];
            float spv = sp[dcol];
            #pragma unroll
            for (int fm = 0; fm < 4; fm++)
            #pragma unroll
            for (int r = 0; r < 4; r++) {
                int rl = fm * 16 + lhi * 4 + r;
                float val = acc[fm][fn][r] + bias;
                float sig = 1.f / (1.f + __expf(-val));
                f16 ov = gate ? (f16)(-8.f * sig * spv) : (f16)sig;
                ldst[rl * 256 + (coll ^ ((rl & 7) << 3))] = ov;
            }
        }
    }
    __syncthreads();

    // ---- Phase 4: per-column 64-step scan (256 threads), in-place:
    //      lds1[s] <- ys (f16), lds2[s] <- cumulative A (f16)
    if (tid < 256) {
        const bool chunk0 = (c == 0);
        const float* ap = act + (size_t)r0 * D_ + (h << 8) + tid;
        float hacc = 0.f, P = 1.f;
        #pragma unroll 4
        for (int s = 0; s < 64; s++) {
            int sw = tid ^ ((s & 7) << 3);
            float ig = (float)lds1[s * 256 + sw];
            float la = (float)lds2[s * 256 + sw];
            float a = __expf(la);
            float xv = ap[(size_t)s * D_];
            float mult;
            if (chunk0 && (s == 0)) { a = 0.f; mult = 1.f; }
            else mult = sqrtf(fmaxf(1.f - a * a, 0.f));
            hacc = fmaf(a, hacc, xv * ig * mult);
            P *= a;
            lds1[s * 256 + sw] = (f16)hacc;
            lds2[s * 256 + sw] = (f16)P;
        }
        // publish chunk aggregate (f32)
        const size_t o = (size_t)(chain * NC_ + c) * 256 + tid;
        He[o] = hacc;
        Pp[o] = P;
    }
    // barrier drains all waves' global stores (compiler emits vmcnt(0))
    __syncthreads();
    if (tid == 0)
        __hip_atomic_store(&flags[chain * NC_ + c], 1,
                           __ATOMIC_RELEASE, __HIP_MEMORY_SCOPE_AGENT);

    // ---- Phase 5: lookback — wait for all predecessor chunks, fold carry
    if (c > 0) {
        if (tid < c) {
            while (__hip_atomic_load(&flags[chain * NC_ + tid], __ATOMIC_RELAXED,
                                     __HIP_MEMORY_SCOPE_AGENT) == 0)
                __builtin_amdgcn_s_sleep(8);
        }
        __syncthreads();
        __threadfence();   // agent acquire: invalidate caches before He/Pp reads
        if (tid < 256) {
            float cv = 0.f;
            for (int j = 0; j < c; j++) {
                const size_t o = (size_t)(chain * NC_ + j) * 256 + tid;
                cv = fmaf(Pp[o], cv, He[o]);
            }
            carry_lds[tid] = cv;
        }
    } else {
        if (tid < 256) carry_lds[tid] = 0.f;
    }
    __syncthreads();

    // ---- Phase 6: apply carry, write final out (512 threads, 2 row-halves)
    {
        const int col = tid & 255;
        const int shalf = tid >> 8;   // rows [shalf*32, +32)
        const float cva = carry_lds[col];
        float* op = out + (size_t)(r0 + shalf * 32) * D_ + (h << 8) + col;
        #pragma unroll 8
        for (int si = 0; si < 32; si++) {
            int s = shalf * 32 + si;
            int sw = col ^ ((s & 7) << 3);
            float ys = (float)lds1[s * 256 + sw];
            float A  = (float)lds2[s * 256 + sw];
            op[(size_t)si * D_] = fmaf(A, cva, ys);
        }
    }
}

// ---------------------------------------------------------------------------
extern "C" void kernel_launch(void* const* d_in, const int* in_sizes, int n_in,
                              void* d_out, int out_size, void* d_ws, size_t ws_size,
                              hipStream_t stream)
{
    const float* act = (const float*)d_in[0];
    // d_in[1] = position_ids: broadcast arange -> reset iff s==0; not read.
    const float* rp  = (const float*)d_in[2];
    const float* wig = (const float*)d_in[3];
    const float* big = (const float*)d_in[4];
    const float* wrg = (const float*)d_in[5];
    const float* brg = (const float*)d_in[6];
    float* out = (float*)d_out;

    // Workspace layout (~5.3 MiB):
    char* ws = (char*)d_ws;
    f16*   wt_ig = (f16*)ws;                                  // 1.25 MiB
    f16*   wt_rg = wt_ig + (size_t)H_ * BW_ * BW_;            // 1.25 MiB
    float* sp    = (float*)(wt_rg + (size_t)H_ * BW_ * BW_);  // 10 KiB
    float* He    = sp + D_;                                   // 1.25 MiB
    float* Pp    = He + (size_t)NBLK * 256;                   // 1.25 MiB
    int*   flags = (int*)(Pp + (size_t)NBLK * 256);           // 5 KiB
    int*   counter = flags + NBLK;                            // 4 B

    // zero flags + ticket counter (in-graph, capturable)
    hipMemsetAsync(flags, 0, (NBLK + 1) * sizeof(int), stream);

    hipLaunchKernelGGL(prep_kernel, dim3(4, 4, H_), dim3(256),
                       0, stream, wig, wrg, rp, wt_ig, wt_rg, sp);
    hipLaunchKernelGGL(fused_kernel, dim3(NBLK), dim3(512),
                       0, stream, act, wt_ig, wt_rg, big, brg, sp,
                       He, Pp, flags, counter, out);
}

// Round 5
// 263.189 us; speedup vs baseline: 2.1763x; 2.1763x over previous
//
#include <hip/hip_runtime.h>
#include <hip/hip_bf16.h>

// Problem constants (RecurrentGemma RG-LRU): B=4, S=2048, D=2560, H=10, bw=256
#define B_  4
#define S_  2048
#define D_  2560
#define H_  10
#define BW_ 256
#define NSUB 64          // sub-chunks per sequence (scan links), 32 rows each
#define SUBL 32          // rows per sub-chunk

typedef _Float16 f16;
typedef _Float16 f16x4 __attribute__((ext_vector_type(4)));
typedef _Float16 f16x8 __attribute__((ext_vector_type(8)));
typedef float    f32x4 __attribute__((ext_vector_type(4)));
typedef unsigned int uint32;

// ---------------------------------------------------------------------------
// Prep: transpose+convert weights to fp16 [H][N][K] via LDS 64x64 tiles
// (coalesced reads AND writes), plus softplus(recurrent_param).
// ---------------------------------------------------------------------------
__global__ __launch_bounds__(256) void prep_kernel(
    const float* __restrict__ wig, const float* __restrict__ wrg,
    const float* __restrict__ rp,
    f16* __restrict__ wt_ig, f16* __restrict__ wt_rg, float* __restrict__ sp)
{
    __shared__ f16 tl[64 * 68];   // +4 pad breaks bank alignment
    const int it = blockIdx.x, jt = blockIdx.y, h = blockIdx.z;
    const int tid = threadIdx.x;

    int flat = ((blockIdx.z * 4 + blockIdx.y) * 4 + blockIdx.x) * 256 + tid;
    if (flat < D_) {
        float x = rp[flat];
        sp[flat] = (x > 20.f) ? x : log1pf(__expf(x));
    }

    for (int m = 0; m < 2; m++) {
        const float* W = m ? wrg : wig;
        f16* WT = m ? wt_rg : wt_ig;
        if (m) __syncthreads();   // m=0 LDS reads done before overwrite
        #pragma unroll
        for (int p = 0; p < 4; p++) {
            int idx = p * 256 + tid;
            int il = idx >> 4, j4 = (idx & 15) << 2;
            float4 v = *(const float4*)&W[(h << 16) + ((it * 64 + il) << 8)
                                          + jt * 64 + j4];
            f16x4 hv;
            hv[0] = (f16)v.x; hv[1] = (f16)v.y; hv[2] = (f16)v.z; hv[3] = (f16)v.w;
            *(f16x4*)&tl[il * 68 + j4] = hv;
        }
        __syncthreads();
        #pragma unroll
        for (int p = 0; p < 4; p++) {
            int idx = p * 256 + tid;
            int jl = idx >> 4, i4 = (idx & 15) << 2;
            f16x4 hv;
            hv[0] = tl[(i4 + 0) * 68 + jl];
            hv[1] = tl[(i4 + 1) * 68 + jl];
            hv[2] = tl[(i4 + 2) * 68 + jl];
            hv[3] = tl[(i4 + 3) * 68 + jl];
            *(f16x4*)&WT[(h << 16) + ((jt * 64 + jl) << 8) + it * 64 + i4] = hv;
        }
    }
}

// ---------------------------------------------------------------------------
// K1: gate-GEMM + sub-chunk scan. Block = 64 rows (2 sub-chunks) x all 256
// head cols. 512 threads = 8 waves: w>>1 = col quadrant, w&1 = gate.
// LDS (64 KB, XOR swizzle byte^=(row&7)<<4):
//   lds1: A-tile x (f16) -> overwritten in-place with xi = x*igate
//   lds2: log_a (f16)
// Scan: 512 threads, 2 threads/column (one per 32-row sub-chunk), writes
// packed {ys:f16, Acum:f16} u32 to global + per-sub-chunk f32 aggregates.
// ---------------------------------------------------------------------------
__global__ __launch_bounds__(512, 4) void fused_kernel(
    const float* __restrict__ act,
    const f16* __restrict__ wt_ig, const f16* __restrict__ wt_rg,
    const float* __restrict__ big, const float* __restrict__ brg,
    const float* __restrict__ sp,
    float2* __restrict__ HP, uint32* __restrict__ packed)
{
    const int c = blockIdx.x;             // 64-row chunk, 0..31
    const int b = blockIdx.y, h = blockIdx.z;
    const int r0 = (b << 11) + (c << 6);  // global row of chunk start
    const int tid = threadIdx.x;
    const int lane = tid & 63, w = tid >> 6;
    const int gate = w & 1;
    const int n0 = (w >> 1) * 64;         // head-col base of this wave
    const int l16 = lane & 15, lhi = lane >> 4;

    __shared__ f16 lds1[64 * 256];
    __shared__ f16 lds2[64 * 256];

    // ---- Phase 1: stage A tile (64 rows x 256 k) fp32 -> fp16, swizzled
    {
        const float* abase = act + (size_t)r0 * D_ + (h << 8);
        #pragma unroll
        for (int i = 0; i < 8; i++) {
            int f = i * 512 + tid;            // float4 index, 4096 total
            int row = f >> 6;
            int k4 = (f & 63) << 2;
            float4 v = *(const float4*)(abase + (size_t)row * D_ + k4);
            f16x4 hv;
            hv[0] = (f16)v.x; hv[1] = (f16)v.y; hv[2] = (f16)v.z; hv[3] = (f16)v.w;
            *(f16x4*)&lds1[row * 256 + (k4 ^ ((row & 7) << 3))] = hv;
        }
    }
    __syncthreads();

    // ---- Phase 2: GEMM. Each wave: 64 rows x 64 cols x one gate, K=256
    const f16* wbase = (gate ? wt_rg : wt_ig) + (h << 16);
    f32x4 acc[4][4] = {};
    f16x8 ar[2][4], br[2][4];

    auto LDA = [&](int ks, f16x8* dst) {
        #pragma unroll
        for (int fm = 0; fm < 4; fm++) {
            int row = fm * 16 + l16;
            int k = ks * 32 + lhi * 8;
            dst[fm] = *(const f16x8*)&lds1[row * 256 + (k ^ ((row & 7) << 3))];
        }
    };
    auto LDB = [&](int ks, f16x8* dst) {
        int ka = ks * 32 + lhi * 8;
        #pragma unroll
        for (int fn = 0; fn < 4; fn++) {
            int j = n0 + fn * 16 + l16;
            dst[fn] = *(const f16x8*)(wbase + (j << 8) + ka);
        }
    };

    LDA(0, ar[0]); LDB(0, br[0]);
    #pragma unroll
    for (int ks = 0; ks < 8; ks++) {
        const int cur = ks & 1;
        if (ks < 7) { LDA(ks + 1, ar[cur ^ 1]); LDB(ks + 1, br[cur ^ 1]); }
        #pragma unroll
        for (int fm = 0; fm < 4; fm++)
        #pragma unroll
        for (int fn = 0; fn < 4; fn++)
            acc[fm][fn] = __builtin_amdgcn_mfma_f32_16x16x32_f16(
                ar[cur][fm], br[cur][fn], acc[fm][fn], 0, 0, 0);
    }
    __syncthreads();   // all lds1 (A-tile) GEMM reads complete

    // ---- Phase 3: epilogue.
    //   gate 0: ig = sigmoid -> lds1 <- x*ig (in-place, same thread RW)
    //   gate 1: la = -8*sig*sp -> lds2
    {
        const float* biasp = gate ? brg : big;
        #pragma unroll
        for (int fn = 0; fn < 4; fn++) {
            int coll = n0 + fn * 16 + l16;         // block-local col 0..255
            int dcol = (h << 8) + coll;
            float bias = biasp[dcol];
            float spv = sp[dcol];
            #pragma unroll
            for (int fm = 0; fm < 4; fm++)
            #pragma unroll
            for (int r = 0; r < 4; r++) {
                int rl = fm * 16 + lhi * 4 + r;
                int off = rl * 256 + (coll ^ ((rl & 7) << 3));
                float val = acc[fm][fn][r] + bias;
                float sig = 1.f / (1.f + __expf(-val));
                if (gate) lds2[off] = (f16)(-8.f * sig * spv);
                else      lds1[off] = (f16)((float)lds1[off] * sig);
            }
        }
    }
    __syncthreads();

    // ---- Phase 4: per-column scan, 2 sub-chunks of 32 steps in parallel.
    {
        const int sub = tid >> 8;     // 0: s in [0,32), 1: s in [32,64)
        const int col = tid & 255;
        const int s0 = sub << 5;
        const bool rst = (c == 0) && (sub == 0);
        uint32* op = packed + (size_t)(r0 + s0) * D_ + (h << 8) + col;
        float hacc = 0.f, P = 1.f;
        #pragma unroll 8
        for (int i = 0; i < 32; i++) {
            int s = s0 + i;
            int sw = col ^ ((s & 7) << 3);
            float xi = (float)lds1[s * 256 + sw];
            float la = (float)lds2[s * 256 + sw];
            float a = __expf(la);
            float mult;
            if (rst && i == 0) { a = 0.f; mult = 1.f; }
            else mult = sqrtf(fmaxf(fmaf(-a, a, 1.f), 0.f));
            hacc = fmaf(a, hacc, xi * mult);
            P *= a;
            union { uint32 u; f16 hh[2]; } cv;
            cv.hh[0] = (f16)hacc; cv.hh[1] = (f16)P;
            op[(size_t)i * D_] = cv.u;
        }
        // publish sub-chunk aggregate (f32)
        const size_t o = ((size_t)((b * H_ + h) * NSUB) + (c * 2 + sub)) * 256 + col;
        HP[o] = make_float2(hacc, P);
    }
}

// ---------------------------------------------------------------------------
// K2: carry fold + apply, one block per 32-row sub-chunk tile.
// Each thread owns one column: folds its chain prefix (batched 8B loads,
// L2/L3-hot), then out[s] = ys[s] + Acum[s]*carry for 32 rows.
// ---------------------------------------------------------------------------
__global__ __launch_bounds__(256) void apply_kernel(
    const uint32* __restrict__ packed, const float2* __restrict__ HP,
    float* __restrict__ out)
{
    const int cc = blockIdx.x;            // sub-chunk 0..63
    const int b = blockIdx.y, h = blockIdx.z;
    const int col = threadIdx.x;
    const float2* hp = HP + (size_t)((b * H_ + h) * NSUB) * 256 + col;

    float cv = 0.f;
    int j = 0;
    for (; j + 8 <= cc; j += 8) {
        float2 v0 = hp[(j + 0) * 256], v1 = hp[(j + 1) * 256];
        float2 v2 = hp[(j + 2) * 256], v3 = hp[(j + 3) * 256];
        float2 v4 = hp[(j + 4) * 256], v5 = hp[(j + 5) * 256];
        float2 v6 = hp[(j + 6) * 256], v7 = hp[(j + 7) * 256];
        cv = fmaf(v0.y, cv, v0.x); cv = fmaf(v1.y, cv, v1.x);
        cv = fmaf(v2.y, cv, v2.x); cv = fmaf(v3.y, cv, v3.x);
        cv = fmaf(v4.y, cv, v4.x); cv = fmaf(v5.y, cv, v5.x);
        cv = fmaf(v6.y, cv, v6.x); cv = fmaf(v7.y, cv, v7.x);
    }
    for (; j < cc; j++) {
        float2 v = hp[j * 256];
        cv = fmaf(v.y, cv, v.x);
    }

    const int gr0 = (b << 11) + (cc << 5);   // global row of sub-chunk
    const uint32* pp = packed + (size_t)gr0 * D_ + (h << 8) + col;
    float* op = out + (size_t)gr0 * D_ + (h << 8) + col;
    #pragma unroll 8
    for (int s = 0; s < SUBL; s++) {
        union { uint32 u; f16 hh[2]; } q;
        q.u = pp[(size_t)s * D_];
        op[(size_t)s * D_] = fmaf((float)q.hh[1], cv, (float)q.hh[0]);
    }
}

// ---------------------------------------------------------------------------
extern "C" void kernel_launch(void* const* d_in, const int* in_sizes, int n_in,
                              void* d_out, int out_size, void* d_ws, size_t ws_size,
                              hipStream_t stream)
{
    const float* act = (const float*)d_in[0];
    // d_in[1] = position_ids: broadcast arange -> reset iff s==0; not read.
    const float* rp  = (const float*)d_in[2];
    const float* wig = (const float*)d_in[3];
    const float* big = (const float*)d_in[4];
    const float* wrg = (const float*)d_in[5];
    const float* brg = (const float*)d_in[6];
    float* out = (float*)d_out;

    // Workspace layout (~87.5 MiB, <= round-1/2 footprint that passed):
    char* ws = (char*)d_ws;
    uint32* packed = (uint32*)ws;                             // 80 MiB
    f16*   wt_ig = (f16*)(ws + (size_t)83886080);             // 1.25 MiB
    f16*   wt_rg = wt_ig + (size_t)H_ * BW_ * BW_;            // 1.25 MiB
    float* sp    = (float*)(wt_rg + (size_t)H_ * BW_ * BW_);  // 10 KiB
    float2* HP   = (float2*)(sp + D_);                        // 5 MiB

    hipLaunchKernelGGL(prep_kernel, dim3(4, 4, H_), dim3(256),
                       0, stream, wig, wrg, rp, wt_ig, wt_rg, sp);
    hipLaunchKernelGGL(fused_kernel, dim3(32, B_, H_), dim3(512),
                       0, stream, act, wt_ig, wt_rg, big, brg, sp, HP, packed);
    hipLaunchKernelGGL(apply_kernel, dim3(NSUB, B_, H_), dim3(256),
                       0, stream, packed, HP, out);
}

// Round 6
// 254.125 us; speedup vs baseline: 2.2540x; 1.0357x over previous
//
#include <hip/hip_runtime.h>
#include <hip/hip_bf16.h>

// Problem constants (RecurrentGemma RG-LRU): B=4, S=2048, D=2560, H=10, bw=256
#define B_  4
#define S_  2048
#define D_  2560
#define H_  10
#define BW_ 256
#define NSUB 64          // scan links per sequence, 32 rows each
#define NCH  (B_ * H_)   // 40 carry chains

typedef _Float16 f16;
typedef _Float16 f16x4 __attribute__((ext_vector_type(4)));
typedef _Float16 f16x8 __attribute__((ext_vector_type(8)));
typedef float    f32x4 __attribute__((ext_vector_type(4)));
typedef unsigned int uint32;

// ---------------------------------------------------------------------------
// Prep: transpose+convert weights to fp16 [H][N][K] via LDS 64x64 tiles
// (coalesced reads AND writes), plus softplus(recurrent_param).
// ---------------------------------------------------------------------------
__global__ __launch_bounds__(256) void prep_kernel(
    const float* __restrict__ wig, const float* __restrict__ wrg,
    const float* __restrict__ rp,
    f16* __restrict__ wt_ig, f16* __restrict__ wt_rg, float* __restrict__ sp)
{
    __shared__ f16 tl[64 * 68];   // +4 pad breaks bank alignment
    const int it = blockIdx.x, jt = blockIdx.y, h = blockIdx.z;
    const int tid = threadIdx.x;

    int flat = ((blockIdx.z * 4 + blockIdx.y) * 4 + blockIdx.x) * 256 + tid;
    if (flat < D_) {
        float x = rp[flat];
        sp[flat] = (x > 20.f) ? x : log1pf(__expf(x));
    }

    for (int m = 0; m < 2; m++) {
        const float* W = m ? wrg : wig;
        f16* WT = m ? wt_rg : wt_ig;
        if (m) __syncthreads();   // m=0 LDS reads done before overwrite
        #pragma unroll
        for (int p = 0; p < 4; p++) {
            int idx = p * 256 + tid;
            int il = idx >> 4, j4 = (idx & 15) << 2;
            float4 v = *(const float4*)&W[(h << 16) + ((it * 64 + il) << 8)
                                          + jt * 64 + j4];
            f16x4 hv;
            hv[0] = (f16)v.x; hv[1] = (f16)v.y; hv[2] = (f16)v.z; hv[3] = (f16)v.w;
            *(f16x4*)&tl[il * 68 + j4] = hv;
        }
        __syncthreads();
        #pragma unroll
        for (int p = 0; p < 4; p++) {
            int idx = p * 256 + tid;
            int jl = idx >> 4, i4 = (idx & 15) << 2;
            f16x4 hv;
            hv[0] = tl[(i4 + 0) * 68 + jl];
            hv[1] = tl[(i4 + 1) * 68 + jl];
            hv[2] = tl[(i4 + 2) * 68 + jl];
            hv[3] = tl[(i4 + 3) * 68 + jl];
            *(f16x4*)&WT[(h << 16) + ((jt * 64 + jl) << 8) + it * 64 + i4] = hv;
        }
    }
}

// ---------------------------------------------------------------------------
// K1 (R2 geometry): gate-GEMM + sub-chunk scan.
// Block: 64 rows (chunk c) x 128 cols (head-half ch), 256 threads = 4 waves:
//   w>>1 = col quadrant (64 cols), w&1 = gate (0=input, 1=recurrent).
// LDS 32 KB (XOR swizzle byte^=(row&7)<<4), phase-reused:
//   phase 1: A-tile f16 [64][256]
//   phase 3: [64][0..128)=igate f16, [64][128..256)=log_a f16
// Scan: 256 threads = 128 cols x 2 sub-chunks of 32 steps; x re-read from
// global (L2-hot); writes packed {ys:f16, Acum:f16} + f32 link aggregates.
// ---------------------------------------------------------------------------
__global__ __launch_bounds__(256, 4) void fused_kernel(
    const float* __restrict__ act,
    const f16* __restrict__ wt_ig, const f16* __restrict__ wt_rg,
    const float* __restrict__ big, const float* __restrict__ brg,
    const float* __restrict__ sp,
    float2* __restrict__ HP, uint32* __restrict__ packed)
{
    const int g  = blockIdx.x;            // b*32 + c
    const int ch = blockIdx.y;            // 0,1 col half
    const int h  = blockIdx.z;            // head
    const int b = g >> 5, c = g & 31;
    const int r0 = (b << 11) + (c << 6);  // global row of chunk start
    const int tid = threadIdx.x;
    const int lane = tid & 63;
    const int w = tid >> 6;
    const int gate = w & 1;
    const int n0 = ch * 128 + (w >> 1) * 64;   // head-col base of this wave
    const int l16 = lane & 15, lhi = lane >> 4;

    __shared__ f16 lds[64 * 256];

    // ---- Phase 1: stage A tile (64 rows x 256 k) fp32 -> fp16, swizzled
    {
        const float* abase = act + (size_t)r0 * D_ + (h << 8);
        #pragma unroll
        for (int i = 0; i < 16; i++) {
            int f = i * 256 + tid;            // float4 index
            int row = f >> 6;
            int k4 = (f & 63) << 2;
            float4 v = *(const float4*)(abase + (size_t)row * D_ + k4);
            f16x4 hv;
            hv[0] = (f16)v.x; hv[1] = (f16)v.y; hv[2] = (f16)v.z; hv[3] = (f16)v.w;
            *(f16x4*)&lds[row * 256 + (k4 ^ ((row & 7) << 3))] = hv;
        }
    }
    __syncthreads();

    // ---- Phase 2: GEMM, 64 rows x 64 cols x one gate per wave, K=256
    const f16* wbase = (gate ? wt_rg : wt_ig) + (h << 16);
    f32x4 acc[4][4] = {};
    f16x8 ar[2][4], br[2][4];

    auto LDA = [&](int ks, f16x8* dst) {
        #pragma unroll
        for (int fm = 0; fm < 4; fm++) {
            int row = fm * 16 + l16;
            int k = ks * 32 + lhi * 8;
            dst[fm] = *(const f16x8*)&lds[row * 256 + (k ^ ((row & 7) << 3))];
        }
    };
    auto LDB = [&](int ks, f16x8* dst) {
        int ka = ks * 32 + lhi * 8;
        #pragma unroll
        for (int fn = 0; fn < 4; fn++) {
            int j = n0 + fn * 16 + l16;
            dst[fn] = *(const f16x8*)(wbase + (j << 8) + ka);
        }
    };

    LDA(0, ar[0]); LDB(0, br[0]);
    #pragma unroll
    for (int ks = 0; ks < 8; ks++) {
        const int cur = ks & 1;
        if (ks < 7) { LDA(ks + 1, ar[cur ^ 1]); LDB(ks + 1, br[cur ^ 1]); }
        #pragma unroll
        for (int fm = 0; fm < 4; fm++)
        #pragma unroll
        for (int fn = 0; fn < 4; fn++)
            acc[fm][fn] = __builtin_amdgcn_mfma_f32_16x16x32_f16(
                ar[cur][fm], br[cur][fn], acc[fm][fn], 0, 0, 0);
    }
    __syncthreads();   // all A-stage reads complete before overwrite

    // ---- Phase 3: epilogue -> igate (half 0) / log_a (half 1), f16 swizzled
    {
        const float* biasp = gate ? brg : big;
        const int halfoff = gate ? 128 : 0;
        #pragma unroll
        for (int fn = 0; fn < 4; fn++) {
            int coll = (w >> 1) * 64 + fn * 16 + l16;   // block-local col 0..127
            int dcol = (h << 8) + ch * 128 + coll;
            float bias = biasp[dcol];
            float spv = sp[dcol];
            #pragma unroll
            for (int fm = 0; fm < 4; fm++)
            #pragma unroll
            for (int r = 0; r < 4; r++) {
                int rl = fm * 16 + lhi * 4 + r;
                float val = acc[fm][fn][r] + bias;
                float sig = 1.f / (1.f + __expf(-val));
                f16 ov = gate ? (f16)(-8.f * sig * spv) : (f16)sig;
                lds[rl * 256 + halfoff + (coll ^ ((rl & 7) << 3))] = ov;
            }
        }
    }
    __syncthreads();

    // ---- Phase 4: per-column scan, 128 cols x 2 sub-chunks of 32 steps
    {
        const int sub = tid >> 7;     // 0: rows [0,32), 1: rows [32,64)
        const int col = tid & 127;
        const int s0 = sub << 5;
        const bool rst0 = (c == 0) && (sub == 0);
        const float* ap = act + (size_t)(r0 + s0) * D_ + (h << 8) + ch * 128 + col;
        uint32* op = packed + (size_t)(r0 + s0) * D_ + (h << 8) + ch * 128 + col;
        float hacc = 0.f, P = 1.f;
        #pragma unroll 8
        for (int i = 0; i < 32; i++) {
            int s = s0 + i;
            int sw = col ^ ((s & 7) << 3);
            float ig = (float)lds[s * 256 + sw];
            float la = (float)lds[s * 256 + 128 + sw];
            float a = __expf(la);
            float xv = ap[(size_t)i * D_];
            float mult;
            if (rst0 && i == 0) { a = 0.f; mult = 1.f; }
            else mult = sqrtf(fmaxf(fmaf(-a, a, 1.f), 0.f));
            hacc = fmaf(a, hacc, xv * ig * mult);
            P *= a;
            union { uint32 u; f16 hh[2]; } cv;
            cv.hh[0] = (f16)hacc; cv.hh[1] = (f16)P;
            op[(size_t)i * D_] = cv.u;
        }
        // publish link aggregate (f32): link = c*2 + sub
        const size_t o = ((size_t)((b * H_ + h) * NSUB) + (c * 2 + sub)) * 256
                         + ch * 128 + col;
        HP[o] = make_float2(hacc, P);
    }
}

// ---------------------------------------------------------------------------
// K2a: materialize carry table [chain][link][col] f32. One block per chain,
// thread = col; sequential over 64 links with 16-wide batched loads (L2-hot).
// ---------------------------------------------------------------------------
__global__ __launch_bounds__(256) void carry_kernel(
    const float2* __restrict__ HP, float* __restrict__ carry)
{
    const int chain = blockIdx.x;   // b*H + h, 0..39
    const int col = threadIdx.x;    // 0..255
    const float2* hp = HP + (size_t)chain * NSUB * 256 + col;
    float* cp = carry + (size_t)chain * NSUB * 256 + col;
    float cv = 0.f;
    for (int l0 = 0; l0 < NSUB; l0 += 16) {
        float2 v[16];
        #pragma unroll
        for (int j = 0; j < 16; j++) v[j] = hp[(l0 + j) * 256];
        #pragma unroll
        for (int j = 0; j < 16; j++) {
            cp[(l0 + j) * 256] = cv;
            cv = fmaf(v[j].y, cv, v[j].x);
        }
    }
}

// ---------------------------------------------------------------------------
// K2b: pure streaming apply: out = ys + Acum * carry[chain][link][col].
// Grid-stride over uint4 (4 packed elems); carry float4 loads are L2/L3-hot.
// ---------------------------------------------------------------------------
__global__ __launch_bounds__(256) void apply_kernel(
    const uint32* __restrict__ packed, const float* __restrict__ carry,
    float* __restrict__ out)
{
    const uint32 n4 = (uint32)(B_ * S_ * D_) / 4;   // 5,242,880
    uint32 i4 = blockIdx.x * 256 + threadIdx.x;
    const uint32 stride = gridDim.x * 256;
    for (; i4 < n4; i4 += stride) {
        uint32 row = i4 / 640;                 // 640 uint4 per row of D=2560
        uint32 d = (i4 - row * 640) * 4;       // 0..2556, multiple of 4
        uint32 b = row >> 11, s = row & (S_ - 1);
        uint32 h = d >> 8, col = d & 255;
        uint32 l = s >> 5;                     // 32-row link index
        const float4 cv = *(const float4*)
            &carry[(((b * H_ + h) * NSUB + l) << 8) + col];
        uint4 p = ((const uint4*)packed)[i4];
        union { uint32 u; f16 hh[2]; } q;
        float4 o;
        q.u = p.x; o.x = fmaf((float)q.hh[1], cv.x, (float)q.hh[0]);
        q.u = p.y; o.y = fmaf((float)q.hh[1], cv.y, (float)q.hh[0]);
        q.u = p.z; o.z = fmaf((float)q.hh[1], cv.z, (float)q.hh[0]);
        q.u = p.w; o.w = fmaf((float)q.hh[1], cv.w, (float)q.hh[0]);
        ((float4*)out)[i4] = o;
    }
}

// ---------------------------------------------------------------------------
extern "C" void kernel_launch(void* const* d_in, const int* in_sizes, int n_in,
                              void* d_out, int out_size, void* d_ws, size_t ws_size,
                              hipStream_t stream)
{
    const float* act = (const float*)d_in[0];
    // d_in[1] = position_ids: broadcast arange -> reset iff s==0; not read.
    const float* rp  = (const float*)d_in[2];
    const float* wig = (const float*)d_in[3];
    const float* big = (const float*)d_in[4];
    const float* wrg = (const float*)d_in[5];
    const float* brg = (const float*)d_in[6];
    float* out = (float*)d_out;

    // Workspace layout (~87.9 MiB):
    //   [0, 80MiB)   packed u32 [B,S,D]
    //   +80MiB       wt_ig f16 (1.31 MiB) | later overlaid by carry f32 table
    //   ...          wt_rg f16 (1.31 MiB) |   (weights dead after fused)
    //   ...          sp f32 [D] (10 KiB)
    //   ...          HP float2 [40][64][256] (5.24 MiB)
    char* ws = (char*)d_ws;
    uint32* packed = (uint32*)ws;
    f16*   wt_ig = (f16*)(ws + (size_t)83886080);
    f16*   wt_rg = wt_ig + (size_t)H_ * BW_ * BW_;
    float* sp    = (float*)(wt_rg + (size_t)H_ * BW_ * BW_);
    float2* HP   = (float2*)(sp + D_);
    float* carry = (float*)wt_ig;   // overlay: 40*64*256 f32 = 2.62 MiB

    hipLaunchKernelGGL(prep_kernel, dim3(4, 4, H_), dim3(256),
                       0, stream, wig, wrg, rp, wt_ig, wt_rg, sp);
    hipLaunchKernelGGL(fused_kernel, dim3(128, 2, H_), dim3(256),
                       0, stream, act, wt_ig, wt_rg, big, brg, sp, HP, packed);
    hipLaunchKernelGGL(carry_kernel, dim3(NCH), dim3(256),
                       0, stream, HP, carry);
    hipLaunchKernelGGL(apply_kernel, dim3(2048), dim3(256),
                       0, stream, packed, carry, out);
}